// Round 5
// baseline (1271.896 us; speedup 1.0000x reference)
//
#include <hip/hip_runtime.h>

#define TT 2048
#define BB 64
#define HH 256   // EMB == HID == 256

typedef _Float16 half2_t __attribute__((ext_vector_type(2)));
typedef _Float16 half8_t __attribute__((ext_vector_type(8)));
typedef float f32x4 __attribute__((ext_vector_type(4)));
typedef int i32x4 __attribute__((ext_vector_type(4)));

static __device__ __forceinline__ float dot2i(int h, int w, float acc) {
  return __builtin_amdgcn_fdot2(__builtin_bit_cast(half2_t, h),
                                __builtin_bit_cast(half2_t, w), acc, false);
}

// ---------------------------------------------------------------------------
// prep: transpose + fp16-convert W_ih and W_hh into [N][K] row-major.
// ---------------------------------------------------------------------------
__global__ void prep_kernel(const float* __restrict__ Wih, const float* __restrict__ Whh,
                            _Float16* __restrict__ WihT, _Float16* __restrict__ WhhT) {
  const int n = blockIdx.x;   // output column
  const int k = threadIdx.x;  // input row
  WihT[n * HH + k] = (_Float16)Wih[k * HH + n];
  WhhT[n * HH + k] = (_Float16)Whh[k * HH + n];
}

// ---------------------------------------------------------------------------
// Part A: U[t][b][n] = (emb[source[b][t]] @ W_ih)[n] + b_ih[n] + b_hh[n], fp16.
// (unchanged — verified correct; scan dominates runtime)
// ---------------------------------------------------------------------------
__global__ __launch_bounds__(256, 2) void embed_gemm_kernel(
    const int* __restrict__ source, const float* __restrict__ emb,
    const _Float16* __restrict__ WihT, const float* __restrict__ b_ih,
    const float* __restrict__ b_hh, _Float16* __restrict__ U) {
  const int t = blockIdx.x;
  const int nbase = blockIdx.y * 64;
  __shared__ __align__(16) _Float16 Bs[64][280];

  const int tid = threadIdx.x;
  for (int c = tid; c < 64 * 32; c += 256) {
    const int n = c >> 5;
    const int ko = (c & 31) * 8;
    *(half8_t*)&Bs[n][ko] = *(const half8_t*)(WihT + (size_t)(nbase + n) * HH + ko);
  }
  __syncthreads();

  const int lane = tid & 63;
  const int wave = tid >> 6;
  const int row16 = lane & 15;
  const int quad = lane >> 4;
  const int b = wave * 16 + row16;              // A-fragment row = batch
  const int src = source[b * TT + t];           // source is [B][T]
  const float* arow = emb + (size_t)src * HH + quad * 8;

  f32x4 acc[4];
#pragma unroll
  for (int ct = 0; ct < 4; ++ct) acc[ct] = (f32x4){0.f, 0.f, 0.f, 0.f};

#pragma unroll
  for (int kt = 0; kt < 8; ++kt) {
    const float4 x0 = *(const float4*)(arow + kt * 32);
    const float4 x1 = *(const float4*)(arow + kt * 32 + 4);
    half8_t af;
    af[0] = (_Float16)x0.x; af[1] = (_Float16)x0.y;
    af[2] = (_Float16)x0.z; af[3] = (_Float16)x0.w;
    af[4] = (_Float16)x1.x; af[5] = (_Float16)x1.y;
    af[6] = (_Float16)x1.z; af[7] = (_Float16)x1.w;
#pragma unroll
    for (int ct = 0; ct < 4; ++ct) {
      const half8_t bf = *(const half8_t*)&Bs[ct * 16 + row16][quad * 8 + kt * 32];
      acc[ct] = __builtin_amdgcn_mfma_f32_16x16x32_f16(af, bf, acc[ct], 0, 0, 0);
    }
  }

#pragma unroll
  for (int ct = 0; ct < 4; ++ct) {
    const int nn = nbase + ct * 16 + row16;     // C col = lane&15
    const float bias = b_ih[nn] + b_hh[nn];
#pragma unroll
    for (int r = 0; r < 4; ++r) {
      const int bb = wave * 16 + quad * 4 + r;  // C row = quad*4 + reg
      U[((size_t)t * BB + bb) * HH + nn] = (_Float16)(acc[ct][r] + bias);
    }
  }
}

// ---------------------------------------------------------------------------
// Part B: recurrence, 512 threads/WG so weights FIT in registers.
//   R4's failure: 256 thr/WG => 128 weight ints/lane, allocator spills to
//   scratch and reloads every step (VGPR_Count pinned at 84 across R1-R4).
//   Now: wave w in [0,8) owns outputs [32w,32w+32); lane l: jo=l>>2, kk=l&3;
//   lane computes outputs {32w+jo, 32w+jo+16} over k-quarter [64kk,64kk+64)
//   => 32 weight ints/lane (+32 hv +misc ~ 80 regs total: fits).
//   h-reads: 8 ds_read_b128/wave, bank-rotated c=(i+2kk)&7 (quarter kk hits
//   bank group 4i+8kk: disjoint, conflict-free). Quad-DPP kk-reduction;
//   lanes kk<2 finalize output m=kk. ONE barrier/step, ping-pong hbuf.
// ---------------------------------------------------------------------------
__global__ __launch_bounds__(512, 1) void rnn_scan_kernel(
    const _Float16* __restrict__ U, const _Float16* __restrict__ WhhT,
    float* __restrict__ out) {
  const int b = blockIdx.x;
  const int tid = threadIdx.x;
  const int w = tid >> 6;   // wave in [0,8)
  const int l = tid & 63;
  const int jo = l >> 2;    // [0,16)
  const int kk = l & 3;     // k-quarter

  __shared__ __align__(16) _Float16 hbuf[2][HH];  // 1 KB ping-pong

  // wr[m][i]: halfs [64kk + 8*((i+2kk)&7) .. +8) of row j = 32w + jo + 16m
  i32x4 wr[2][8];
#pragma unroll
  for (int m = 0; m < 2; ++m) {
    const _Float16* base = WhhT + (size_t)(32 * w + jo + 16 * m) * HH + 64 * kk;
#pragma unroll
    for (int i = 0; i < 8; ++i) {
      const int c = (i + 2 * kk) & 7;
      wr[m][i] = *(const i32x4*)(base + 8 * c);
    }
  }
  // Pin (insurance against remat/spill; only 32 regs now)
#pragma unroll
  for (int m = 0; m < 2; ++m)
#pragma unroll
    for (int i = 0; i < 8; ++i) {
      asm volatile("" : "+v"(wr[m][i]));
    }

  if (tid < HH) hbuf[0][tid] = (_Float16)0.f;  // h0 = 0

  const int jstar = 32 * w + jo + 16 * (kk & 1);  // output lanes kk<2 finalize
  const _Float16* Up = U + b * HH + jstar;
  _Float16 uA = Up[0];
  _Float16 uB = Up[(size_t)BB * HH];
  float hn = 0.f;
  __syncthreads();

  for (int t = 0; t < TT; ++t) {
    // ---- h-quarter reads, bank-rotated chunk order (conflict-free) ----
    const i32x4* hq = (const i32x4*)(hbuf[t & 1] + 64 * kk);
    i32x4 hv[8];
#pragma unroll
    for (int i = 0; i < 8; ++i) hv[i] = hq[(i + 2 * kk) & 7];

    // ---- partial dots: 2 outputs x 64 MACs = 64 fdot2, 2 indep chains ----
    float pa[2] = {0.f, 0.f};
#pragma unroll
    for (int i = 0; i < 8; ++i) {
      const i32x4 h4 = hv[i];
#pragma unroll
      for (int m = 0; m < 2; ++m) {
        const i32x4 w4 = wr[m][i];
        pa[m] = dot2i(h4[0], w4[0], pa[m]);
        pa[m] = dot2i(h4[1], w4[1], pa[m]);
        pa[m] = dot2i(h4[2], w4[2], pa[m]);
        pa[m] = dot2i(h4[3], w4[3], pa[m]);
      }
    }

    // ---- reduce over kk (quad lanes) via DPP quad_perm ----
#pragma unroll
    for (int m = 0; m < 2; ++m) {
      int x = __float_as_int(pa[m]);
      pa[m] += __int_as_float(__builtin_amdgcn_mov_dpp(x, 0xB1, 0xF, 0xF, true));  // xor1
      x = __float_as_int(pa[m]);
      pa[m] += __int_as_float(__builtin_amdgcn_mov_dpp(x, 0x4E, 0xF, 0xF, true));  // xor2
    }
    const float sum = (kk & 1) ? pa[1] : pa[0];

    const float a = (float)uA + sum;
    // tanh(a) = 1 - 2/(exp(2a)+1)
    const float e = __builtin_amdgcn_exp2f(a * 2.885390081777927f);  // 2*log2(e)
    hn = 1.f - 2.f * __builtin_amdgcn_rcpf(e + 1.f);
    if (kk < 2) hbuf[(t + 1) & 1][jstar] = (_Float16)hn;

    // u prefetch, 2 steps ahead (vmcnt off the critical path)
    uA = uB;
    uB = Up[(size_t)((t + 2) & (TT - 1)) * (BB * HH)];

    __syncthreads();  // the single per-step barrier
  }
  if (kk < 2) out[(size_t)b * HH + jstar] = hn;
}

// ---------------------------------------------------------------------------
extern "C" void kernel_launch(void* const* d_in, const int* in_sizes, int n_in,
                              void* d_out, int out_size, void* d_ws, size_t ws_size,
                              hipStream_t stream) {
  const int*   source = (const int*)d_in[0];
  const float* emb    = (const float*)d_in[1];
  const float* Wih    = (const float*)d_in[2];
  const float* Whh    = (const float*)d_in[3];
  const float* bih    = (const float*)d_in[4];
  const float* bhh    = (const float*)d_in[5];
  float* out = (float*)d_out;

  char* ws = (char*)d_ws;
  _Float16* U    = (_Float16*)ws;                    // 2048*64*256*2 = 67,108,864 B
  _Float16* WihT = (_Float16*)(ws + 67108864);       // 131,072 B
  _Float16* WhhT = (_Float16*)(ws + 67239936);       // 131,072 B (total ~67.4 MB)

  prep_kernel<<<dim3(256), dim3(256), 0, stream>>>(Wih, Whh, WihT, WhhT);
  embed_gemm_kernel<<<dim3(TT, 4), dim3(256), 0, stream>>>(source, emb, WihT, bih, bhh, U);
  rnn_scan_kernel<<<dim3(BB), dim3(512), 0, stream>>>(U, WhhT, out);
}

// Round 6
// 1107.448 us; speedup vs baseline: 1.1485x; 1.1485x over previous
//
#include <hip/hip_runtime.h>

#define TT 2048
#define BB 64
#define HH 256   // EMB == HID == 256

typedef _Float16 half2_t __attribute__((ext_vector_type(2)));
typedef _Float16 half8_t __attribute__((ext_vector_type(8)));
typedef float f32x4 __attribute__((ext_vector_type(4)));
typedef int i32x4 __attribute__((ext_vector_type(4)));

static __device__ __forceinline__ float dot2i(int h, int w, float acc) {
  return __builtin_amdgcn_fdot2(__builtin_bit_cast(half2_t, h),
                                __builtin_bit_cast(half2_t, w), acc, false);
}

// ---------------------------------------------------------------------------
// prep: transpose + fp16-convert W_ih and W_hh into [N][K] row-major.
// ---------------------------------------------------------------------------
__global__ void prep_kernel(const float* __restrict__ Wih, const float* __restrict__ Whh,
                            _Float16* __restrict__ WihT, _Float16* __restrict__ WhhT) {
  const int n = blockIdx.x;   // output column
  const int k = threadIdx.x;  // input row
  WihT[n * HH + k] = (_Float16)Wih[k * HH + n];
  WhhT[n * HH + k] = (_Float16)Whh[k * HH + n];
}

// ---------------------------------------------------------------------------
// Part A: U[t][b][n] = (emb[source[b][t]] @ W_ih)[n] + b_ih[n] + b_hh[n], fp16.
// (unchanged — verified correct; scan dominates runtime)
// ---------------------------------------------------------------------------
__global__ __launch_bounds__(256, 2) void embed_gemm_kernel(
    const int* __restrict__ source, const float* __restrict__ emb,
    const _Float16* __restrict__ WihT, const float* __restrict__ b_ih,
    const float* __restrict__ b_hh, _Float16* __restrict__ U) {
  const int t = blockIdx.x;
  const int nbase = blockIdx.y * 64;
  __shared__ __align__(16) _Float16 Bs[64][280];

  const int tid = threadIdx.x;
  for (int c = tid; c < 64 * 32; c += 256) {
    const int n = c >> 5;
    const int ko = (c & 31) * 8;
    *(half8_t*)&Bs[n][ko] = *(const half8_t*)(WihT + (size_t)(nbase + n) * HH + ko);
  }
  __syncthreads();

  const int lane = tid & 63;
  const int wave = tid >> 6;
  const int row16 = lane & 15;
  const int quad = lane >> 4;
  const int b = wave * 16 + row16;              // A-fragment row = batch
  const int src = source[b * TT + t];           // source is [B][T]
  const float* arow = emb + (size_t)src * HH + quad * 8;

  f32x4 acc[4];
#pragma unroll
  for (int ct = 0; ct < 4; ++ct) acc[ct] = (f32x4){0.f, 0.f, 0.f, 0.f};

#pragma unroll
  for (int kt = 0; kt < 8; ++kt) {
    const float4 x0 = *(const float4*)(arow + kt * 32);
    const float4 x1 = *(const float4*)(arow + kt * 32 + 4);
    half8_t af;
    af[0] = (_Float16)x0.x; af[1] = (_Float16)x0.y;
    af[2] = (_Float16)x0.z; af[3] = (_Float16)x0.w;
    af[4] = (_Float16)x1.x; af[5] = (_Float16)x1.y;
    af[6] = (_Float16)x1.z; af[7] = (_Float16)x1.w;
#pragma unroll
    for (int ct = 0; ct < 4; ++ct) {
      const half8_t bf = *(const half8_t*)&Bs[ct * 16 + row16][quad * 8 + kt * 32];
      acc[ct] = __builtin_amdgcn_mfma_f32_16x16x32_f16(af, bf, acc[ct], 0, 0, 0);
    }
  }

#pragma unroll
  for (int ct = 0; ct < 4; ++ct) {
    const int nn = nbase + ct * 16 + row16;     // C col = lane&15
    const float bias = b_ih[nn] + b_hh[nn];
#pragma unroll
    for (int r = 0; r < 4; ++r) {
      const int bb = wave * 16 + quad * 4 + r;  // C row = quad*4 + reg
      U[((size_t)t * BB + bb) * HH + nn] = (_Float16)(acc[ct][r] + bias);
    }
  }
}

// ---------------------------------------------------------------------------
// Part B: recurrence — R4 structure + amdgpu_waves_per_eu(1,1).
//   Root cause of R1-R5 plateau: with tiny LDS the allocator targets 8
//   waves/SIMD => ~64-VGPR budget, so the 128 weight ints/lane spill to
//   scratch and reload through L2 every step (~240 ns/step, L2-BW-bound;
//   VGPR_Count 84/48 at needs 128/64 = the fingerprint). waves_per_eu(1,1)
//   sets the occupancy target to 1 wave/EU (exactly our launch shape: 64
//   WGs x 4 waves on 64 CUs), giving a 512-VGPR budget so weights stay
//   resident. asm pin blocks rematerialization of the loads.
// ---------------------------------------------------------------------------
__global__ __launch_bounds__(256)
__attribute__((amdgpu_waves_per_eu(1, 1)))
void rnn_scan_kernel(
    const _Float16* __restrict__ U, const _Float16* __restrict__ WhhT,
    float* __restrict__ out) {
  const int b = blockIdx.x;
  const int tid = threadIdx.x;
  const int w = tid >> 6;
  const int l = tid & 63;
  const int jj = l >> 2;
  const int kk = l & 3;

  __shared__ __align__(16) _Float16 hbuf[2][HH];  // 1 KB ping-pong

  // wr[m][i]: halfs [64kk + 8*((i+2kk)&7) .. +8) of W^T row 64w+jj+16m
  i32x4 wr[4][8];
#pragma unroll
  for (int m = 0; m < 4; ++m) {
    const _Float16* base = WhhT + (size_t)(64 * w + jj + 16 * m) * HH + 64 * kk;
#pragma unroll
    for (int i = 0; i < 8; ++i) {
      const int c = (i + 2 * kk) & 7;
      wr[m][i] = *(const i32x4*)(base + 8 * c);
    }
  }
  // Pin: asm "writes" each reg -> not rematerializable.
#pragma unroll
  for (int m = 0; m < 4; ++m)
#pragma unroll
    for (int i = 0; i < 8; ++i) {
      asm volatile("" : "+v"(wr[m][i]));
    }

  hbuf[0][tid] = (_Float16)0.f;  // h0 = 0

  const int jstar = 64 * w + jj + 16 * kk;  // output this lane finalizes
  const _Float16* Up = U + b * HH + jstar;
  _Float16 uA = Up[0];
  _Float16 uB = Up[(size_t)BB * HH];
  float hn = 0.f;
  __syncthreads();

  for (int t = 0; t < TT; ++t) {
    // ---- h-quarter reads, bank-rotated chunk order (conflict-free) ----
    const i32x4* hq = (const i32x4*)(hbuf[t & 1] + 64 * kk);
    i32x4 hv[8];
#pragma unroll
    for (int i = 0; i < 8; ++i) hv[i] = hq[(i + 2 * kk) & 7];

    // ---- partial dots: 4 outputs x 64 MACs = 128 fdot2, 4 indep chains ----
    float pa[4] = {0.f, 0.f, 0.f, 0.f};
#pragma unroll
    for (int i = 0; i < 8; ++i) {
      const i32x4 h4 = hv[i];
#pragma unroll
      for (int m = 0; m < 4; ++m) {
        const i32x4 w4 = wr[m][i];
        pa[m] = dot2i(h4[0], w4[0], pa[m]);
        pa[m] = dot2i(h4[1], w4[1], pa[m]);
        pa[m] = dot2i(h4[2], w4[2], pa[m]);
        pa[m] = dot2i(h4[3], w4[3], pa[m]);
      }
    }

    // ---- reduce over kk (quad lanes) via DPP quad_perm ----
#pragma unroll
    for (int m = 0; m < 4; ++m) {
      int x = __float_as_int(pa[m]);
      pa[m] += __int_as_float(__builtin_amdgcn_mov_dpp(x, 0xB1, 0xF, 0xF, true));  // xor1
      x = __float_as_int(pa[m]);
      pa[m] += __int_as_float(__builtin_amdgcn_mov_dpp(x, 0x4E, 0xF, 0xF, true));  // xor2
    }
    // lane finalizes output m == kk (cndmask chain)
    const float sum = (kk & 1) ? ((kk & 2) ? pa[3] : pa[1])
                               : ((kk & 2) ? pa[2] : pa[0]);

    const float a = (float)uA + sum;
    // tanh(a) = 1 - 2/(exp(2a)+1)
    const float e = __builtin_amdgcn_exp2f(a * 2.885390081777927f);  // 2*log2(e)
    hn = 1.f - 2.f * __builtin_amdgcn_rcpf(e + 1.f);
    hbuf[(t + 1) & 1][jstar] = (_Float16)hn;

    // u prefetch, 2 steps ahead (vmcnt off the critical path)
    uA = uB;
    uB = Up[(size_t)((t + 2) & (TT - 1)) * (BB * HH)];

    __syncthreads();  // the single per-step barrier
  }
  out[(size_t)b * HH + jstar] = hn;
}

// ---------------------------------------------------------------------------
extern "C" void kernel_launch(void* const* d_in, const int* in_sizes, int n_in,
                              void* d_out, int out_size, void* d_ws, size_t ws_size,
                              hipStream_t stream) {
  const int*   source = (const int*)d_in[0];
  const float* emb    = (const float*)d_in[1];
  const float* Wih    = (const float*)d_in[2];
  const float* Whh    = (const float*)d_in[3];
  const float* bih    = (const float*)d_in[4];
  const float* bhh    = (const float*)d_in[5];
  float* out = (float*)d_out;

  char* ws = (char*)d_ws;
  _Float16* U    = (_Float16*)ws;                    // 2048*64*256*2 = 67,108,864 B
  _Float16* WihT = (_Float16*)(ws + 67108864);       // 131,072 B
  _Float16* WhhT = (_Float16*)(ws + 67239936);       // 131,072 B (total ~67.4 MB)

  prep_kernel<<<dim3(256), dim3(256), 0, stream>>>(Wih, Whh, WihT, WhhT);
  embed_gemm_kernel<<<dim3(TT, 4), dim3(256), 0, stream>>>(source, emb, WihT, bih, bhh, U);
  rnn_scan_kernel<<<dim3(BB), dim3(256), 0, stream>>>(U, WhhT, out);
}